// Round 2
// baseline (811.133 us; speedup 1.0000x reference)
//
#include <hip/hip_runtime.h>

typedef float  f32x4 __attribute__((ext_vector_type(4)));
typedef short  s16x8 __attribute__((ext_vector_type(8)));
typedef unsigned short u16x4 __attribute__((ext_vector_type(4)));

// B=2, S=2048, D=1024, H=16, dh=64 ; bh = b*16+h in [0,32)

static __device__ __forceinline__ unsigned short f2bf(float f) {
  unsigned u = __builtin_bit_cast(unsigned, f);
  u += 0x7fffu + ((u >> 16) & 1u);          // RNE
  return (unsigned short)(u >> 16);
}

static __device__ __forceinline__ void glds16(const void* g, void* l) {
  __builtin_amdgcn_global_load_lds(
      (const __attribute__((address_space(1))) unsigned int*)g,
      (__attribute__((address_space(3))) unsigned int*)l, 16, 0, 0);
}

// ---------------- fp32 -> bf16 convert (vectorized) ----------------
__global__ __launch_bounds__(256) void cvt_bf16(const float4* __restrict__ src,
                                                u16x4* __restrict__ dst) {
  int i = blockIdx.x * 256 + threadIdx.x;
  float4 v = src[i];
  u16x4 o = { f2bf(v.x), f2bf(v.y), f2bf(v.z), f2bf(v.w) };
  dst[i] = o;
}

// ---------------- NT GEMM: C[m,n] = sum_k A[m,k]*B[n,k] (+bias)*scale ------
// M=4096 N=1024 K=1024. 128x128 tile, 4 waves (2x2 of 64x64), BK=64.
// mode 0: bf16 out at [bh][s][64] (Q/K) ; mode 1: bf16 out transposed [bh][d][s] (V)
// mode 2: fp32 out at m*1024+n (final projection)
__global__ __launch_bounds__(256) void gemm_nt(const unsigned short* __restrict__ A,
                                               const unsigned short* __restrict__ Bm,
                                               const float* __restrict__ bias,
                                               float scale, int mode,
                                               void* __restrict__ out) {
  __shared__ unsigned short at[128 * 64];
  __shared__ unsigned short bt[128 * 64];
  const int tid = threadIdx.x, lane = tid & 63, wid = tid >> 6;
  const int l15 = lane & 15, l4 = lane >> 4;
  const int nb = (blockIdx.x & 7) * 128, mb = (blockIdx.x >> 3) * 128;
  const int wm = (wid >> 1) * 64, wn = (wid & 1) * 64;

  f32x4 acc[4][4];
#pragma unroll
  for (int mt = 0; mt < 4; ++mt)
#pragma unroll
    for (int nt = 0; nt < 4; ++nt) acc[mt][nt] = {0.f, 0.f, 0.f, 0.f};

  for (int k0 = 0; k0 < 1024; k0 += 64) {
#pragma unroll
    for (int i = 0; i < 4; ++i) {
      int slotbase = (i * 4 + wid) * 64;
      int slot = slotbase + lane;
      int row = slot >> 3;
      int cs = (slot & 7) ^ (row & 7);   // pre-swizzled global source
      glds16(&A[(mb + row) * 1024 + k0 + cs * 8], &at[slotbase * 8]);
      glds16(&Bm[(nb + row) * 1024 + k0 + cs * 8], &bt[slotbase * 8]);
    }
    __syncthreads();
#pragma unroll
    for (int ks = 0; ks < 2; ++ks) {
      s16x8 af[4], bf[4];
#pragma unroll
      for (int mt = 0; mt < 4; ++mt) {
        int row = wm + mt * 16 + l15;
        af[mt] = *(const s16x8*)((const char*)&at[row * 64] +
                                 ((ks * 64 + l4 * 16) ^ ((row & 7) << 4)));
      }
#pragma unroll
      for (int nt = 0; nt < 4; ++nt) {
        int row = wn + nt * 16 + l15;
        bf[nt] = *(const s16x8*)((const char*)&bt[row * 64] +
                                 ((ks * 64 + l4 * 16) ^ ((row & 7) << 4)));
      }
#pragma unroll
      for (int mt = 0; mt < 4; ++mt)
#pragma unroll
        for (int nt = 0; nt < 4; ++nt)
          acc[mt][nt] = __builtin_amdgcn_mfma_f32_16x16x32_bf16(af[mt], bf[nt],
                                                                acc[mt][nt], 0, 0, 0);
    }
    __syncthreads();
  }

#pragma unroll
  for (int mt = 0; mt < 4; ++mt)
#pragma unroll
    for (int nt = 0; nt < 4; ++nt) {
      int n = nb + wn + nt * 16 + l15;
      float bvv = bias ? bias[n] : 0.0f;
      int m0 = mb + wm + mt * 16 + l4 * 4;
      if (mode == 0) {
#pragma unroll
        for (int r = 0; r < 4; ++r) {
          int m = m0 + r;
          float v = (acc[mt][nt][r] + bvv) * scale;
          int bb = m >> 11, s = m & 2047, hh = n >> 6, d = n & 63;
          ((unsigned short*)out)[(size_t)((bb * 16 + hh) * 2048 + s) * 64 + d] = f2bf(v);
        }
      } else if (mode == 1) {
        int bb = m0 >> 11, s0 = m0 & 2047, hh = n >> 6, d = n & 63;
        u16x4 p;
#pragma unroll
        for (int r = 0; r < 4; ++r) p[r] = f2bf(acc[mt][nt][r] + bvv);
        *(u16x4*)&((unsigned short*)out)[(size_t)((bb * 16 + hh) * 64 + d) * 2048 + s0] = p;
      } else {
#pragma unroll
        for (int r = 0; r < 4; ++r) {
          int m = m0 + r;
          ((float*)out)[(size_t)m * 1024 + n] = acc[mt][nt][r] + bvv;
        }
      }
    }
}

// ---------------- phase 1: l[bh][q] = sum_k exp(s(q,k)) -------------------
// swapped mfma(K,Q): C[k,q]; scores lane-local; fixed m=0 (logits bounded small)
__global__ __launch_bounds__(256) void attn_sumexp(const unsigned short* __restrict__ Q,
                                                   const unsigned short* __restrict__ K,
                                                   float* __restrict__ lsum) {
  __shared__ unsigned short kt[64 * 64];
  const int tid = threadIdx.x, lane = tid & 63, wid = tid >> 6;
  const int l15 = lane & 15, l4 = lane >> 4;
  const int bh = blockIdx.x >> 5;
  const int qb = (blockIdx.x & 31) * 64;
  const int q = qb + wid * 16 + l15;

  s16x8 qf[2];
  qf[0] = *(const s16x8*)&Q[(bh * 2048 + q) * 64 + l4 * 8];
  qf[1] = *(const s16x8*)&Q[(bh * 2048 + q) * 64 + 32 + l4 * 8];

  float acc = 0.f;
  for (int k0 = 0; k0 < 2048; k0 += 64) {
#pragma unroll
    for (int i = 0; i < 2; ++i) {
      int slotbase = (i * 4 + wid) * 64;
      int slot = slotbase + lane;
      int row = slot >> 3;
      int cs = (slot & 7) ^ (row & 7);
      glds16(&K[(bh * 2048 + k0 + row) * 64 + cs * 8], &kt[slotbase * 8]);
    }
    __syncthreads();
#pragma unroll
    for (int ks = 0; ks < 4; ++ks) {
      f32x4 c = {0.f, 0.f, 0.f, 0.f};
      int row = ks * 16 + l15;
#pragma unroll
      for (int t = 0; t < 2; ++t) {
        s16x8 a = *(const s16x8*)((const char*)&kt[row * 64] +
                                  ((t * 64 + l4 * 16) ^ ((row & 7) << 4)));
        c = __builtin_amdgcn_mfma_f32_16x16x32_bf16(a, qf[t], c, 0, 0, 0);
      }
      acc += __expf(c[0]) + __expf(c[1]) + __expf(c[2]) + __expf(c[3]);
    }
    __syncthreads();
  }
  acc += __shfl_xor(acc, 16);
  acc += __shfl_xor(acc, 32);
  if (l4 == 0) lsum[bh * 2048 + q] = acc;
}

// ---------------- phase 2: w writes + O = w @ V ---------------------------
__global__ __launch_bounds__(256) void attn_wv(const unsigned short* __restrict__ Q,
                                               const unsigned short* __restrict__ K,
                                               const unsigned short* __restrict__ Vt,
                                               const float* __restrict__ lsum,
                                               float* __restrict__ wout,
                                               unsigned short* __restrict__ wv) {
  __shared__ unsigned short kt[64 * 64];
  __shared__ unsigned short vt[64 * 64];
  __shared__ unsigned short pt[4][16 * 64];
  const int tid = threadIdx.x, lane = tid & 63, wid = tid >> 6;
  const int l15 = lane & 15, l4 = lane >> 4;
  const int bh = blockIdx.x >> 5;
  const int qb = (blockIdx.x & 31) * 64;
  const int q = qb + wid * 16 + l15;

  s16x8 qf[2];
  qf[0] = *(const s16x8*)&Q[(bh * 2048 + q) * 64 + l4 * 8];
  qf[1] = *(const s16x8*)&Q[(bh * 2048 + q) * 64 + 32 + l4 * 8];
  float rcpl = 1.0f / lsum[bh * 2048 + q];
  float* wrow = &wout[((size_t)bh * 2048 + q) * 2048];

  f32x4 oacc[4];
#pragma unroll
  for (int dt = 0; dt < 4; ++dt) oacc[dt] = {0.f, 0.f, 0.f, 0.f};

  for (int k0i = 0; k0i < 32; ++k0i) {
    int k0 = k0i * 64;
#pragma unroll
    for (int i = 0; i < 2; ++i) {
      int slotbase = (i * 4 + wid) * 64;
      int slot = slotbase + lane;
      int row = slot >> 3;
      int cs = (slot & 7) ^ (row & 7);
      glds16(&K[(bh * 2048 + k0 + row) * 64 + cs * 8], &kt[slotbase * 8]);
      glds16(&Vt[(size_t)(bh * 64 + row) * 2048 + k0 + cs * 8], &vt[slotbase * 8]);
    }
    __syncthreads();
    // QK^T swapped: C[k_local, q]
#pragma unroll
    for (int ks = 0; ks < 4; ++ks) {
      f32x4 c = {0.f, 0.f, 0.f, 0.f};
      int row = ks * 16 + l15;
#pragma unroll
      for (int t = 0; t < 2; ++t) {
        s16x8 a = *(const s16x8*)((const char*)&kt[row * 64] +
                                  ((t * 64 + l4 * 16) ^ ((row & 7) << 4)));
        c = __builtin_amdgcn_mfma_f32_16x16x32_bf16(a, qf[t], c, 0, 0, 0);
      }
      float w0 = __expf(c[0]) * rcpl, w1 = __expf(c[1]) * rcpl;
      float w2 = __expf(c[2]) * rcpl, w3 = __expf(c[3]) * rcpl;
      f32x4 w4 = {w0, w1, w2, w3};
      *(f32x4*)&wrow[k0 + ks * 16 + l4 * 4] = w4;          // coalesced float4
      u16x4 pb = {f2bf(w0), f2bf(w1), f2bf(w2), f2bf(w3)};
      *(u16x4*)((char*)&pt[wid][l15 * 64] +
                ((ks * 32 + l4 * 8) ^ ((l15 & 7) << 4))) = pb;
    }
    // PV: O[q,d] += P[q,k] * V[k,d]   (pt wave-private; vt barriered above)
#pragma unroll
    for (int t = 0; t < 2; ++t) {
      s16x8 pa = *(const s16x8*)((const char*)&pt[wid][l15 * 64] +
                                 ((t * 64 + l4 * 16) ^ ((l15 & 7) << 4)));
#pragma unroll
      for (int dt = 0; dt < 4; ++dt) {
        int row = dt * 16 + l15;
        s16x8 vb = *(const s16x8*)((const char*)&vt[row * 64] +
                                   ((t * 64 + l4 * 16) ^ ((row & 7) << 4)));
        oacc[dt] = __builtin_amdgcn_mfma_f32_16x16x32_bf16(pa, vb, oacc[dt], 0, 0, 0);
      }
    }
    __syncthreads();
  }
  int b = bh >> 4, h = bh & 15;
#pragma unroll
  for (int dt = 0; dt < 4; ++dt)
#pragma unroll
    for (int r = 0; r < 4; ++r) {
      int sq = qb + wid * 16 + l4 * 4 + r;
      int d = dt * 16 + l15;
      wv[(size_t)(b * 2048 + sq) * 1024 + h * 64 + d] = f2bf(oacc[dt][r]);
    }
}

extern "C" void kernel_launch(void* const* d_in, const int* in_sizes, int n_in,
                              void* d_out, int out_size, void* d_ws, size_t ws_size,
                              hipStream_t stream) {
  const float* x  = (const float*)d_in[0];
  const float* Wq = (const float*)d_in[1];
  const float* bq = (const float*)d_in[2];
  const float* Wk = (const float*)d_in[3];
  const float* Wv = (const float*)d_in[4];
  const float* bv = (const float*)d_in[5];
  const float* bo = (const float*)d_in[7];
  const float* Wo = (const float*)d_in[6];
  float* out  = (float*)d_out;
  float* wout = out + 4194304;   // w region of d_out (out is 2*2048*1024)

  // workspace layout (40.3 MB):
  unsigned short* xb  = (unsigned short*)d_ws;  // 4,194,304 elems (8 MB)
  unsigned short* Wqb = xb + 4194304;           // 1,048,576
  unsigned short* Wkb = Wqb + 1048576;
  unsigned short* Wvb = Wkb + 1048576;
  unsigned short* Wob = Wvb + 1048576;
  unsigned short* Qb  = Wob + 1048576;          // [bh][s][64]  (8 MB)
  unsigned short* Kb  = Qb + 4194304;           // [bh][s][64]  (8 MB)
  unsigned short* Vtb = Kb + 4194304;           // [bh][d][s]   (8 MB)
  float* lsum = (float*)(Vtb + 4194304);        // [bh][s] (256 KB)
  unsigned short* wvb = xb;                     // alias: xb dead after V GEMM

  cvt_bf16<<<4096, 256, 0, stream>>>((const float4*)x,  (u16x4*)xb);
  cvt_bf16<<<1024, 256, 0, stream>>>((const float4*)Wq, (u16x4*)Wqb);
  cvt_bf16<<<1024, 256, 0, stream>>>((const float4*)Wk, (u16x4*)Wkb);
  cvt_bf16<<<1024, 256, 0, stream>>>((const float4*)Wv, (u16x4*)Wvb);
  cvt_bf16<<<1024, 256, 0, stream>>>((const float4*)Wo, (u16x4*)Wob);

  const float kscale = 0.35355339059327373f;    // 64^-0.25
  gemm_nt<<<256, 256, 0, stream>>>(xb, Wqb, bq, kscale, 0, Qb);
  gemm_nt<<<256, 256, 0, stream>>>(xb, Wkb, nullptr, kscale, 0, Kb);
  gemm_nt<<<256, 256, 0, stream>>>(xb, Wvb, bv, 1.0f, 1, Vtb);

  attn_sumexp<<<1024, 256, 0, stream>>>(Qb, Kb, lsum);
  attn_wv<<<1024, 256, 0, stream>>>(Qb, Kb, Vtb, lsum, wout, wvb);

  gemm_nt<<<256, 256, 0, stream>>>(wvb, Wob, bo, 1.0f, 2, out);
}

// Round 3
// 759.950 us; speedup vs baseline: 1.0674x; 1.0674x over previous
//
#include <hip/hip_runtime.h>

typedef float  f32x4 __attribute__((ext_vector_type(4)));
typedef short  s16x8 __attribute__((ext_vector_type(8)));
typedef unsigned short u16x4 __attribute__((ext_vector_type(4)));

// B=2, S=2048, D=1024, H=16, dh=64 ; bh = b*16+h in [0,32)

static __device__ __forceinline__ unsigned short f2bf(float f) {
  unsigned u = __builtin_bit_cast(unsigned, f);
  u += 0x7fffu + ((u >> 16) & 1u);          // RNE
  return (unsigned short)(u >> 16);
}

static __device__ __forceinline__ void glds16(const void* g, void* l) {
  __builtin_amdgcn_global_load_lds(
      (const __attribute__((address_space(1))) unsigned int*)g,
      (__attribute__((address_space(3))) unsigned int*)l, 16, 0, 0);
}

static __device__ __forceinline__ void ntst4(float* p, f32x4 v) {
  __builtin_nontemporal_store(v, (f32x4*)p);
}

// stage one 64x64 bf16 tile (8 KB) into LDS: 2 glds16 per wave, 4 waves.
// gsrc points at tile origin; gstride = row stride in elements.
// LDS dest linear; global source pre-swizzled (inverse of read XOR).
static __device__ __forceinline__ void stage64(const unsigned short* gsrc, int gstride,
                                               unsigned short* lbase, int wid, int lane) {
#pragma unroll
  for (int i = 0; i < 2; ++i) {
    int slotbase = (i * 4 + wid) * 64;
    int slot = slotbase + lane;
    int row = slot >> 3;
    int cs = (slot & 7) ^ (row & 7);
    glds16(&gsrc[(size_t)row * gstride + cs * 8], &lbase[slotbase * 8]);
  }
}

// ---------------- fused fp32 -> bf16 convert ----------------
__global__ __launch_bounds__(256) void cvt_all(
    const float4* __restrict__ x,  const float4* __restrict__ wq,
    const float4* __restrict__ wk, const float4* __restrict__ wv,
    const float4* __restrict__ wo,
    u16x4* __restrict__ xb,  u16x4* __restrict__ wqb,
    u16x4* __restrict__ wkb, u16x4* __restrict__ wvb,
    u16x4* __restrict__ wob) {
  int b = blockIdx.x;
  const float4* s; u16x4* d; int o;
  if (b < 4096)      { s = x;  d = xb;  o = b; }
  else if (b < 5120) { s = wq; d = wqb; o = b - 4096; }
  else if (b < 6144) { s = wk; d = wkb; o = b - 5120; }
  else if (b < 7168) { s = wv; d = wvb; o = b - 6144; }
  else               { s = wo; d = wob; o = b - 7168; }
  int i = o * 256 + threadIdx.x;
  float4 v = s[i];
  u16x4 r = { f2bf(v.x), f2bf(v.y), f2bf(v.z), f2bf(v.w) };
  d[i] = r;
}

// ---------------- NT GEMM body: C[m,n] = sum_k A[m,k]*B[n,k] (+bias)*scale --
// M=4096 N=1024 K=1024. 128x128 tile, 4 waves (2x2 of 64x64), BK=64.
// mode 0: bf16 out [bh][s][64] (Q/K); mode 1: bf16 out transposed [bh][d][s] (V)
// mode 2: fp32 out m*1024+n (final projection)
static __device__ __forceinline__ void gemm_body(
    int bid, unsigned short* at, unsigned short* bt,
    const unsigned short* __restrict__ A, const unsigned short* __restrict__ Bm,
    const float* __restrict__ bias, float scale, int mode, void* __restrict__ out) {
  const int tid = threadIdx.x, lane = tid & 63, wid = tid >> 6;
  const int l15 = lane & 15, l4 = lane >> 4;
  const int nb = (bid & 7) * 128, mb = (bid >> 3) * 128;
  const int wm = (wid >> 1) * 64, wn = (wid & 1) * 64;

  f32x4 acc[4][4];
#pragma unroll
  for (int mt = 0; mt < 4; ++mt)
#pragma unroll
    for (int nt = 0; nt < 4; ++nt) acc[mt][nt] = {0.f, 0.f, 0.f, 0.f};

  for (int k0 = 0; k0 < 1024; k0 += 64) {
#pragma unroll
    for (int i = 0; i < 4; ++i) {
      int slotbase = (i * 4 + wid) * 64;
      int slot = slotbase + lane;
      int row = slot >> 3;
      int cs = (slot & 7) ^ (row & 7);   // pre-swizzled global source
      glds16(&A[(mb + row) * 1024 + k0 + cs * 8], &at[slotbase * 8]);
      glds16(&Bm[(nb + row) * 1024 + k0 + cs * 8], &bt[slotbase * 8]);
    }
    __syncthreads();
#pragma unroll
    for (int ks = 0; ks < 2; ++ks) {
      s16x8 af[4], bf[4];
#pragma unroll
      for (int mt = 0; mt < 4; ++mt) {
        int row = wm + mt * 16 + l15;
        af[mt] = *(const s16x8*)((const char*)&at[row * 64] +
                                 ((ks * 64 + l4 * 16) ^ ((row & 7) << 4)));
      }
#pragma unroll
      for (int nt = 0; nt < 4; ++nt) {
        int row = wn + nt * 16 + l15;
        bf[nt] = *(const s16x8*)((const char*)&bt[row * 64] +
                                 ((ks * 64 + l4 * 16) ^ ((row & 7) << 4)));
      }
#pragma unroll
      for (int mt = 0; mt < 4; ++mt)
#pragma unroll
        for (int nt = 0; nt < 4; ++nt)
          acc[mt][nt] = __builtin_amdgcn_mfma_f32_16x16x32_bf16(af[mt], bf[nt],
                                                                acc[mt][nt], 0, 0, 0);
    }
    __syncthreads();
  }

#pragma unroll
  for (int mt = 0; mt < 4; ++mt)
#pragma unroll
    for (int nt = 0; nt < 4; ++nt) {
      int n = nb + wn + nt * 16 + l15;
      float bvv = bias ? bias[n] : 0.0f;
      int m0 = mb + wm + mt * 16 + l4 * 4;
      if (mode == 0) {
#pragma unroll
        for (int r = 0; r < 4; ++r) {
          int m = m0 + r;
          float v = (acc[mt][nt][r] + bvv) * scale;
          int bb = m >> 11, s = m & 2047, hh = n >> 6, d = n & 63;
          ((unsigned short*)out)[(size_t)((bb * 16 + hh) * 2048 + s) * 64 + d] = f2bf(v);
        }
      } else if (mode == 1) {
        int bb = m0 >> 11, s0 = m0 & 2047, hh = n >> 6, d = n & 63;
        u16x4 p;
#pragma unroll
        for (int r = 0; r < 4; ++r) p[r] = f2bf(acc[mt][nt][r] + bvv);
        *(u16x4*)&((unsigned short*)out)[(size_t)((bb * 16 + hh) * 64 + d) * 2048 + s0] = p;
      } else {
#pragma unroll
        for (int r = 0; r < 4; ++r) {
          int m = m0 + r;
          ((float*)out)[(size_t)m * 1024 + n] = acc[mt][nt][r] + bvv;
        }
      }
    }
}

// fused Q/K/V projections: 768 blocks (3 per CU), shared A-panel L2 reuse
__global__ __launch_bounds__(256) void gemm_qkv(
    const unsigned short* __restrict__ xb,
    const unsigned short* __restrict__ Wqb, const unsigned short* __restrict__ Wkb,
    const unsigned short* __restrict__ Wvb,
    const float* __restrict__ bq, const float* __restrict__ bv,
    unsigned short* __restrict__ Qb, unsigned short* __restrict__ Kb,
    unsigned short* __restrict__ Vtb, float kscale) {
  __shared__ unsigned short at[128 * 64];
  __shared__ unsigned short bt[128 * 64];
  int sw = (blockIdx.x & 7) * 96 + (blockIdx.x >> 3);   // bijective XCD swizzle (768%8==0)
  int op = sw >> 8, bid = sw & 255;
  if (op == 0)      gemm_body(bid, at, bt, xb, Wqb, bq,      kscale, 0, Qb);
  else if (op == 1) gemm_body(bid, at, bt, xb, Wkb, nullptr, kscale, 0, Kb);
  else              gemm_body(bid, at, bt, xb, Wvb, bv,      1.0f,   1, Vtb);
}

__global__ __launch_bounds__(256) void gemm_o(
    const unsigned short* __restrict__ A, const unsigned short* __restrict__ Wob,
    const float* __restrict__ bo, float* __restrict__ out) {
  __shared__ unsigned short at[128 * 64];
  __shared__ unsigned short bt[128 * 64];
  int sw = (blockIdx.x & 7) * 32 + (blockIdx.x >> 3);   // 256%8==0
  gemm_body(sw, at, bt, A, Wob, bo, 1.0f, 2, out);
}

// ---------------- phase 1: l[bh][q] = sum_k exp(s(q,k)) -------------------
// QBLK=128 (wave handles 32 q), double-buffered K tiles, counted vmcnt.
__global__ __launch_bounds__(256) void attn_sumexp(const unsigned short* __restrict__ Q,
                                                   const unsigned short* __restrict__ K,
                                                   float* __restrict__ lsum) {
  __shared__ unsigned short kt[2][64 * 64];
  const int tid = threadIdx.x, lane = tid & 63, wid = tid >> 6;
  const int l15 = lane & 15, l4 = lane >> 4;
  const int sw = (blockIdx.x & 7) * 64 + (blockIdx.x >> 3);  // 512%8==0
  const int bh = sw >> 4;
  const int qb = (sw & 15) * 128;
  const int q0 = qb + wid * 32 + l15;

  s16x8 qf[2][2];
#pragma unroll
  for (int qg = 0; qg < 2; ++qg)
#pragma unroll
    for (int t = 0; t < 2; ++t)
      qf[qg][t] = *(const s16x8*)&Q[(size_t)(bh * 2048 + q0 + qg * 16) * 64 + t * 32 + l4 * 8];

  float acc0 = 0.f, acc1 = 0.f;
  const unsigned short* Kbh = &K[(size_t)bh * 2048 * 64];

  stage64(&Kbh[0], 64, &kt[0][0], wid, lane);
  int cur = 0;
  for (int t = 0; t < 32; ++t) {
    if (t < 31) {
      stage64(&Kbh[(size_t)(t + 1) * 64 * 64], 64, &kt[cur ^ 1][0], wid, lane);
      asm volatile("s_waitcnt vmcnt(2)" ::: "memory");   // cur tile landed; next in flight
    } else {
      asm volatile("s_waitcnt vmcnt(0)" ::: "memory");
    }
    __builtin_amdgcn_sched_barrier(0);
    __builtin_amdgcn_s_barrier();
#pragma unroll
    for (int ks = 0; ks < 4; ++ks) {
      int row = ks * 16 + l15;
      const char* rbase = (const char*)&kt[cur][row * 64];
      s16x8 a0 = *(const s16x8*)(rbase + ((l4 * 16) ^ ((row & 7) << 4)));
      s16x8 a1 = *(const s16x8*)(rbase + ((64 + l4 * 16) ^ ((row & 7) << 4)));
      f32x4 c0 = {0.f, 0.f, 0.f, 0.f}, c1 = {0.f, 0.f, 0.f, 0.f};
      c0 = __builtin_amdgcn_mfma_f32_16x16x32_bf16(a0, qf[0][0], c0, 0, 0, 0);
      c0 = __builtin_amdgcn_mfma_f32_16x16x32_bf16(a1, qf[0][1], c0, 0, 0, 0);
      c1 = __builtin_amdgcn_mfma_f32_16x16x32_bf16(a0, qf[1][0], c1, 0, 0, 0);
      c1 = __builtin_amdgcn_mfma_f32_16x16x32_bf16(a1, qf[1][1], c1, 0, 0, 0);
      acc0 += __expf(c0[0]) + __expf(c0[1]) + __expf(c0[2]) + __expf(c0[3]);
      acc1 += __expf(c1[0]) + __expf(c1[1]) + __expf(c1[2]) + __expf(c1[3]);
    }
    __builtin_amdgcn_s_barrier();
    cur ^= 1;
  }
  acc0 += __shfl_xor(acc0, 16); acc0 += __shfl_xor(acc0, 32);
  acc1 += __shfl_xor(acc1, 16); acc1 += __shfl_xor(acc1, 32);
  if (l4 == 0) {
    lsum[bh * 2048 + q0] = acc0;
    lsum[bh * 2048 + q0 + 16] = acc1;
  }
}

// ---------------- phase 2: w writes + O = w @ V ---------------------------
// QBLK=128, double-buffered K+V tiles, counted vmcnt, nontemporal w stores.
__global__ __launch_bounds__(256) void attn_wv(const unsigned short* __restrict__ Q,
                                               const unsigned short* __restrict__ K,
                                               const unsigned short* __restrict__ Vt,
                                               const float* __restrict__ lsum,
                                               float* __restrict__ wout,
                                               unsigned short* __restrict__ wv) {
  __shared__ unsigned short kt[2][64 * 64];
  __shared__ unsigned short vt[2][64 * 64];
  __shared__ unsigned short pt[4][2][16 * 64];
  const int tid = threadIdx.x, lane = tid & 63, wid = tid >> 6;
  const int l15 = lane & 15, l4 = lane >> 4;
  const int sw = (blockIdx.x & 7) * 64 + (blockIdx.x >> 3);
  const int bh = sw >> 4;
  const int qb = (sw & 15) * 128;
  const int q0 = qb + wid * 32 + l15;

  s16x8 qf[2][2];
#pragma unroll
  for (int qg = 0; qg < 2; ++qg)
#pragma unroll
    for (int t = 0; t < 2; ++t)
      qf[qg][t] = *(const s16x8*)&Q[(size_t)(bh * 2048 + q0 + qg * 16) * 64 + t * 32 + l4 * 8];
  float rcpl0 = 1.0f / lsum[bh * 2048 + q0];
  float rcpl1 = 1.0f / lsum[bh * 2048 + q0 + 16];
  float* wrow0 = &wout[((size_t)bh * 2048 + q0) * 2048];
  float* wrow1 = wrow0 + (size_t)16 * 2048;

  f32x4 oacc[2][4];
#pragma unroll
  for (int qg = 0; qg < 2; ++qg)
#pragma unroll
    for (int dt = 0; dt < 4; ++dt) oacc[qg][dt] = {0.f, 0.f, 0.f, 0.f};

  const unsigned short* Kbh = &K[(size_t)bh * 2048 * 64];
  const unsigned short* Vbh = &Vt[(size_t)bh * 64 * 2048];

  stage64(&Kbh[0], 64, &kt[0][0], wid, lane);
  stage64(&Vbh[0], 2048, &vt[0][0], wid, lane);
  int cur = 0;
  for (int t = 0; t < 32; ++t) {
    int k0 = t * 64;
    if (t < 31) {
      stage64(&Kbh[(size_t)(t + 1) * 64 * 64], 64, &kt[cur ^ 1][0], wid, lane);
      stage64(&Vbh[k0 + 64], 2048, &vt[cur ^ 1][0], wid, lane);
      asm volatile("s_waitcnt vmcnt(4)" ::: "memory");
    } else {
      asm volatile("s_waitcnt vmcnt(0)" ::: "memory");
    }
    __builtin_amdgcn_sched_barrier(0);
    __builtin_amdgcn_s_barrier();

    // QK^T (swapped: C[k,q]) + exp + w store + P tile
#pragma unroll
    for (int ks = 0; ks < 4; ++ks) {
      int row = ks * 16 + l15;
      const char* rbase = (const char*)&kt[cur][row * 64];
      s16x8 a0 = *(const s16x8*)(rbase + ((l4 * 16) ^ ((row & 7) << 4)));
      s16x8 a1 = *(const s16x8*)(rbase + ((64 + l4 * 16) ^ ((row & 7) << 4)));
      f32x4 c0 = {0.f, 0.f, 0.f, 0.f}, c1 = {0.f, 0.f, 0.f, 0.f};
      c0 = __builtin_amdgcn_mfma_f32_16x16x32_bf16(a0, qf[0][0], c0, 0, 0, 0);
      c0 = __builtin_amdgcn_mfma_f32_16x16x32_bf16(a1, qf[0][1], c0, 0, 0, 0);
      c1 = __builtin_amdgcn_mfma_f32_16x16x32_bf16(a0, qf[1][0], c1, 0, 0, 0);
      c1 = __builtin_amdgcn_mfma_f32_16x16x32_bf16(a1, qf[1][1], c1, 0, 0, 0);
      float w00 = __expf(c0[0]) * rcpl0, w01 = __expf(c0[1]) * rcpl0;
      float w02 = __expf(c0[2]) * rcpl0, w03 = __expf(c0[3]) * rcpl0;
      float w10 = __expf(c1[0]) * rcpl1, w11 = __expf(c1[1]) * rcpl1;
      float w12 = __expf(c1[2]) * rcpl1, w13 = __expf(c1[3]) * rcpl1;
      ntst4(&wrow0[k0 + ks * 16 + l4 * 4], (f32x4){w00, w01, w02, w03});
      ntst4(&wrow1[k0 + ks * 16 + l4 * 4], (f32x4){w10, w11, w12, w13});
      u16x4 pb0 = {f2bf(w00), f2bf(w01), f2bf(w02), f2bf(w03)};
      u16x4 pb1 = {f2bf(w10), f2bf(w11), f2bf(w12), f2bf(w13)};
      *(u16x4*)((char*)&pt[wid][0][l15 * 64] + ((ks * 32 + l4 * 8) ^ ((l15 & 7) << 4))) = pb0;
      *(u16x4*)((char*)&pt[wid][1][l15 * 64] + ((ks * 32 + l4 * 8) ^ ((l15 & 7) << 4))) = pb1;
    }
    // PV: O[q,d] += P[q,k] * V[k,d]  (pt wave-private)
#pragma unroll
    for (int t2 = 0; t2 < 2; ++t2) {
      s16x8 pa0 = *(const s16x8*)((char*)&pt[wid][0][l15 * 64] +
                                  ((t2 * 64 + l4 * 16) ^ ((l15 & 7) << 4)));
      s16x8 pa1 = *(const s16x8*)((char*)&pt[wid][1][l15 * 64] +
                                  ((t2 * 64 + l4 * 16) ^ ((l15 & 7) << 4)));
#pragma unroll
      for (int dt = 0; dt < 4; ++dt) {
        int vrow = dt * 16 + l15;
        s16x8 vb = *(const s16x8*)((const char*)&vt[cur][vrow * 64] +
                                   ((t2 * 64 + l4 * 16) ^ ((vrow & 7) << 4)));
        oacc[0][dt] = __builtin_amdgcn_mfma_f32_16x16x32_bf16(pa0, vb, oacc[0][dt], 0, 0, 0);
        oacc[1][dt] = __builtin_amdgcn_mfma_f32_16x16x32_bf16(pa1, vb, oacc[1][dt], 0, 0, 0);
      }
    }
    __builtin_amdgcn_s_barrier();
    cur ^= 1;
  }
  int b = bh >> 4, h = bh & 15;
#pragma unroll
  for (int qg = 0; qg < 2; ++qg)
#pragma unroll
    for (int dt = 0; dt < 4; ++dt)
#pragma unroll
      for (int r = 0; r < 4; ++r) {
        int sq = qb + wid * 32 + qg * 16 + l4 * 4 + r;
        int d = dt * 16 + l15;
        wv[(size_t)(b * 2048 + sq) * 1024 + h * 64 + d] = f2bf(oacc[qg][dt][r]);
      }
}

extern "C" void kernel_launch(void* const* d_in, const int* in_sizes, int n_in,
                              void* d_out, int out_size, void* d_ws, size_t ws_size,
                              hipStream_t stream) {
  const float* x  = (const float*)d_in[0];
  const float* Wq = (const float*)d_in[1];
  const float* bq = (const float*)d_in[2];
  const float* Wk = (const float*)d_in[3];
  const float* Wv = (const float*)d_in[4];
  const float* bv = (const float*)d_in[5];
  const float* Wo = (const float*)d_in[6];
  const float* bo = (const float*)d_in[7];
  float* out  = (float*)d_out;
  float* wout = out + 4194304;   // w region of d_out (out is 2*2048*1024)

  // workspace layout (40.3 MB):
  unsigned short* xb  = (unsigned short*)d_ws;  // 4,194,304 elems (8 MB)
  unsigned short* Wqb = xb + 4194304;           // 1,048,576
  unsigned short* Wkb = Wqb + 1048576;
  unsigned short* Wvb = Wkb + 1048576;
  unsigned short* Wob = Wvb + 1048576;
  unsigned short* Qb  = Wob + 1048576;          // [bh][s][64]  (8 MB)
  unsigned short* Kb  = Qb + 4194304;           // [bh][s][64]  (8 MB)
  unsigned short* Vtb = Kb + 4194304;           // [bh][d][s]   (8 MB)
  float* lsum = (float*)(Vtb + 4194304);        // [bh][s] (256 KB)
  unsigned short* wvb = xb;                     // alias: xb dead after V GEMM

  cvt_all<<<8192, 256, 0, stream>>>((const float4*)x, (const float4*)Wq,
                                    (const float4*)Wk, (const float4*)Wv,
                                    (const float4*)Wo,
                                    (u16x4*)xb, (u16x4*)Wqb, (u16x4*)Wkb,
                                    (u16x4*)Wvb, (u16x4*)Wob);

  const float kscale = 0.35355339059327373f;    // 64^-0.25
  gemm_qkv<<<768, 256, 0, stream>>>(xb, Wqb, Wkb, Wvb, bq, bv, Qb, Kb, Vtb, kscale);

  attn_sumexp<<<512, 256, 0, stream>>>(Qb, Kb, lsum);
  attn_wv<<<512, 256, 0, stream>>>(Qb, Kb, Vtb, lsum, wout, wvb);

  gemm_o<<<256, 256, 0, stream>>>(wvb, Wob, bo, out);
}

// Round 5
// 758.802 us; speedup vs baseline: 1.0690x; 1.0015x over previous
//
#include <hip/hip_runtime.h>

typedef float  f32x4 __attribute__((ext_vector_type(4)));
typedef short  s16x8 __attribute__((ext_vector_type(8)));
typedef unsigned short u16x4 __attribute__((ext_vector_type(4)));

// B=2, S=2048, D=1024, H=16, dh=64 ; bh = b*16+h in [0,32)

static __device__ __forceinline__ unsigned short f2bf(float f) {
  unsigned u = __builtin_bit_cast(unsigned, f);
  u += 0x7fffu + ((u >> 16) & 1u);          // RNE
  return (unsigned short)(u >> 16);
}

static __device__ __forceinline__ void glds16(const void* g, void* l) {
  __builtin_amdgcn_global_load_lds(
      (const __attribute__((address_space(1))) unsigned int*)g,
      (__attribute__((address_space(3))) unsigned int*)l, 16, 0, 0);
}

static __device__ __forceinline__ void ntst4(float* p, f32x4 v) {
  __builtin_nontemporal_store(v, (f32x4*)p);
}

// stage an R x 64 bf16 tile into LDS. LDS dest linear (glds16 lane-ordered);
// global source pre-swizzled with the inverse of the read-side XOR.
// LDS[row][c] = G[row][c ^ (row&7)] in 8-elem chunks.
template <int R>
static __device__ __forceinline__ void stage_rows(const unsigned short* g, int gstride,
                                                  unsigned short* l, int wid, int lane) {
#pragma unroll
  for (int i = 0; i < R / 32; ++i) {
    int slotbase = (i * 4 + wid) * 64;
    int slot = slotbase + lane;
    int row = slot >> 3;
    int cs = (slot & 7) ^ (row & 7);
    glds16(&g[(size_t)row * gstride + cs * 8], &l[slotbase * 8]);
  }
}

// ---------------- fused fp32 -> bf16 convert ----------------
__global__ __launch_bounds__(256) void cvt_all(
    const float4* __restrict__ x,  const float4* __restrict__ wq,
    const float4* __restrict__ wk, const float4* __restrict__ wv,
    const float4* __restrict__ wo,
    u16x4* __restrict__ xb,  u16x4* __restrict__ wqb,
    u16x4* __restrict__ wkb, u16x4* __restrict__ wvb,
    u16x4* __restrict__ wob) {
  int b = blockIdx.x;
  const float4* s; u16x4* d; int o;
  if (b < 4096)      { s = x;  d = xb;  o = b; }
  else if (b < 5120) { s = wq; d = wqb; o = b - 4096; }
  else if (b < 6144) { s = wk; d = wkb; o = b - 5120; }
  else if (b < 7168) { s = wv; d = wvb; o = b - 6144; }
  else               { s = wo; d = wob; o = b - 7168; }
  int i = o * 256 + threadIdx.x;
  float4 v = s[i];
  u16x4 r = { f2bf(v.x), f2bf(v.y), f2bf(v.z), f2bf(v.w) };
  d[i] = r;
}

// ---------------- fused QKV NT GEMM, prefetch-dbuf ----------------
// C[m,n] = sum_k A[m,k]*B[n,k] (+bias)*scale. M=4096 N=1024 K=1024.
// 128x128 tile, 4 waves (2x2 of 64x64), BK=64, double-buffered LDS,
// STAGE(t+1) issued before compute(t), one vmcnt(0)+barrier per step.
// mode 0: bf16 out [bh][s][64] (Q/K); mode 1: bf16 out transposed [bh][d][s] (V)
__global__ __launch_bounds__(256) void gemm_qkv(
    const unsigned short* __restrict__ xb,
    const unsigned short* __restrict__ Wqb, const unsigned short* __restrict__ Wkb,
    const unsigned short* __restrict__ Wvb,
    const float* __restrict__ bq, const float* __restrict__ bv,
    unsigned short* __restrict__ Qb, unsigned short* __restrict__ Kb,
    unsigned short* __restrict__ Vtb, float kscale) {
  __shared__ unsigned short at[2][128 * 64];
  __shared__ unsigned short bt[2][128 * 64];
  const int tid = threadIdx.x, lane = tid & 63, wid = tid >> 6;
  const int l15 = lane & 15, l4 = lane >> 4;
  int sw = (blockIdx.x & 7) * 96 + (blockIdx.x >> 3);   // bijective (768%8==0)
  int op = sw >> 8, bid = sw & 255;
  const unsigned short* A = xb;
  const unsigned short* Bm; const float* bias; float scale; int mode;
  void* outp;
  if (op == 0)      { Bm = Wqb; bias = bq;      scale = kscale; mode = 0; outp = Qb; }
  else if (op == 1) { Bm = Wkb; bias = nullptr; scale = kscale; mode = 0; outp = Kb; }
  else              { Bm = Wvb; bias = bv;      scale = 1.0f;   mode = 1; outp = Vtb; }

  const int nb = (bid & 7) * 128, mb = (bid >> 3) * 128;
  const int wm = (wid >> 1) * 64, wn = (wid & 1) * 64;

  f32x4 acc[4][4];
#pragma unroll
  for (int mt = 0; mt < 4; ++mt)
#pragma unroll
    for (int nt = 0; nt < 4; ++nt) acc[mt][nt] = {0.f, 0.f, 0.f, 0.f};

  stage_rows<128>(&A[(size_t)mb * 1024], 1024, at[0], wid, lane);
  stage_rows<128>(&Bm[(size_t)nb * 1024], 1024, bt[0], wid, lane);
  asm volatile("s_waitcnt vmcnt(0)" ::: "memory");
  __builtin_amdgcn_sched_barrier(0);
  __builtin_amdgcn_s_barrier();

  int cur = 0;
  for (int t = 0; t < 16; ++t) {
    if (t < 15) {
      stage_rows<128>(&A[(size_t)mb * 1024 + (t + 1) * 64], 1024, at[cur ^ 1], wid, lane);
      stage_rows<128>(&Bm[(size_t)nb * 1024 + (t + 1) * 64], 1024, bt[cur ^ 1], wid, lane);
    }
#pragma unroll
    for (int ks = 0; ks < 2; ++ks) {
      s16x8 af[4], bf[4];
#pragma unroll
      for (int mt = 0; mt < 4; ++mt) {
        int row = wm + mt * 16 + l15;
        af[mt] = *(const s16x8*)((const char*)&at[cur][row * 64] +
                                 ((ks * 64 + l4 * 16) ^ ((row & 7) << 4)));
      }
#pragma unroll
      for (int nt = 0; nt < 4; ++nt) {
        int row = wn + nt * 16 + l15;
        bf[nt] = *(const s16x8*)((const char*)&bt[cur][row * 64] +
                                 ((ks * 64 + l4 * 16) ^ ((row & 7) << 4)));
      }
#pragma unroll
      for (int mt = 0; mt < 4; ++mt)
#pragma unroll
        for (int nt = 0; nt < 4; ++nt)
          acc[mt][nt] = __builtin_amdgcn_mfma_f32_16x16x32_bf16(af[mt], bf[nt],
                                                                acc[mt][nt], 0, 0, 0);
    }
    if (t < 15) {
      asm volatile("s_waitcnt vmcnt(0)" ::: "memory");
      __builtin_amdgcn_sched_barrier(0);
      __builtin_amdgcn_s_barrier();
      cur ^= 1;
    }
  }

#pragma unroll
  for (int mt = 0; mt < 4; ++mt)
#pragma unroll
    for (int nt = 0; nt < 4; ++nt) {
      int n = nb + wn + nt * 16 + l15;
      float bvv = bias ? bias[n] : 0.0f;
      int m0 = mb + wm + mt * 16 + l4 * 4;
      if (mode == 0) {
#pragma unroll
        for (int r = 0; r < 4; ++r) {
          int m = m0 + r;
          float v = (acc[mt][nt][r] + bvv) * scale;
          int bb = m >> 11, s = m & 2047, hh = n >> 6, d = n & 63;
          ((unsigned short*)outp)[(size_t)((bb * 16 + hh) * 2048 + s) * 64 + d] = f2bf(v);
        }
      } else {
        int bb = m0 >> 11, s0 = m0 & 2047, hh = n >> 6, d = n & 63;
        u16x4 p;
#pragma unroll
        for (int r = 0; r < 4; ++r) p[r] = f2bf(acc[mt][nt][r] + bvv);
        *(u16x4*)&((unsigned short*)outp)[(size_t)((bb * 16 + hh) * 64 + d) * 2048 + s0] = p;
      }
    }
}

// ---------------- output projection: 128x64 tiles, prefetch-dbuf ----------
__global__ __launch_bounds__(256) void gemm_o(
    const unsigned short* __restrict__ A, const unsigned short* __restrict__ Wob,
    const float* __restrict__ bo, float* __restrict__ out) {
  __shared__ unsigned short at[2][128 * 64];
  __shared__ unsigned short bt[2][64 * 64];
  const int tid = threadIdx.x, lane = tid & 63, wid = tid >> 6;
  const int l15 = lane & 15, l4 = lane >> 4;
  int sw = (blockIdx.x & 7) * 64 + (blockIdx.x >> 3);   // 512%8==0
  const int nb = (sw & 15) * 64, mb = (sw >> 4) * 128;
  const int wm = (wid >> 1) * 64, wn = (wid & 1) * 32;

  f32x4 acc[4][2];
#pragma unroll
  for (int mt = 0; mt < 4; ++mt)
#pragma unroll
    for (int nt = 0; nt < 2; ++nt) acc[mt][nt] = {0.f, 0.f, 0.f, 0.f};

  stage_rows<128>(&A[(size_t)mb * 1024], 1024, at[0], wid, lane);
  stage_rows<64>(&Wob[(size_t)nb * 1024], 1024, bt[0], wid, lane);
  asm volatile("s_waitcnt vmcnt(0)" ::: "memory");
  __builtin_amdgcn_sched_barrier(0);
  __builtin_amdgcn_s_barrier();

  int cur = 0;
  for (int t = 0; t < 16; ++t) {
    if (t < 15) {
      stage_rows<128>(&A[(size_t)mb * 1024 + (t + 1) * 64], 1024, at[cur ^ 1], wid, lane);
      stage_rows<64>(&Wob[(size_t)nb * 1024 + (t + 1) * 64], 1024, bt[cur ^ 1], wid, lane);
    }
#pragma unroll
    for (int ks = 0; ks < 2; ++ks) {
      s16x8 af[4], bf[2];
#pragma unroll
      for (int mt = 0; mt < 4; ++mt) {
        int row = wm + mt * 16 + l15;
        af[mt] = *(const s16x8*)((const char*)&at[cur][row * 64] +
                                 ((ks * 64 + l4 * 16) ^ ((row & 7) << 4)));
      }
#pragma unroll
      for (int nt = 0; nt < 2; ++nt) {
        int row = wn + nt * 16 + l15;
        bf[nt] = *(const s16x8*)((const char*)&bt[cur][row * 64] +
                                 ((ks * 64 + l4 * 16) ^ ((row & 7) << 4)));
      }
#pragma unroll
      for (int mt = 0; mt < 4; ++mt)
#pragma unroll
        for (int nt = 0; nt < 2; ++nt)
          acc[mt][nt] = __builtin_amdgcn_mfma_f32_16x16x32_bf16(af[mt], bf[nt],
                                                                acc[mt][nt], 0, 0, 0);
    }
    if (t < 15) {
      asm volatile("s_waitcnt vmcnt(0)" ::: "memory");
      __builtin_amdgcn_sched_barrier(0);
      __builtin_amdgcn_s_barrier();
      cur ^= 1;
    }
  }

#pragma unroll
  for (int mt = 0; mt < 4; ++mt)
#pragma unroll
    for (int nt = 0; nt < 2; ++nt) {
      int n = nb + wn + nt * 16 + l15;
      float bvv = bo[n];
      int m0 = mb + wm + mt * 16 + l4 * 4;
#pragma unroll
      for (int r = 0; r < 4; ++r)
        out[(size_t)(m0 + r) * 1024 + n] = acc[mt][nt][r] + bvv;
    }
}

// ---------------- fused attention: pass1 sumexp, pass2 w + PV -------------
// One block per (bh, 128-q tile); 4 waves x 32 q. Triple-buffered K/V tiles,
// 2-deep prefetch, counted vmcnt (never 0 mid-loop). w stored nontemporal.
__global__ __launch_bounds__(256) void attn_fused(const unsigned short* __restrict__ Q,
                                                  const unsigned short* __restrict__ K,
                                                  const unsigned short* __restrict__ Vt,
                                                  float* __restrict__ wout,
                                                  unsigned short* __restrict__ wv) {
  __shared__ unsigned short kt[3][64 * 64];
  __shared__ unsigned short vt[3][64 * 64];
  __shared__ unsigned short pt[4][2][16 * 64];
  const int tid = threadIdx.x, lane = tid & 63, wid = tid >> 6;
  const int l15 = lane & 15, l4 = lane >> 4;
  const int sw = (blockIdx.x & 7) * 64 + (blockIdx.x >> 3);  // 512%8==0
  const int bh = sw >> 4;
  const int qb = (sw & 15) * 128;
  const int q0 = qb + wid * 32 + l15;

  s16x8 qf[2][2];
#pragma unroll
  for (int qg = 0; qg < 2; ++qg)
#pragma unroll
    for (int t = 0; t < 2; ++t)
      qf[qg][t] = *(const s16x8*)&Q[(size_t)(bh * 2048 + q0 + qg * 16) * 64 + t * 32 + l4 * 8];

  const unsigned short* Kbh = &K[(size_t)bh * 2048 * 64];
  const unsigned short* Vbh = &Vt[(size_t)bh * 64 * 2048];

  // ---- pass 1: l = sum_k exp(s) ----
  float acc0 = 0.f, acc1 = 0.f;
  stage_rows<64>(&Kbh[0], 64, kt[0], wid, lane);
  stage_rows<64>(&Kbh[64 * 64], 64, kt[1], wid, lane);
  for (int t = 0; t < 32; ++t) {
    if (t < 30) {
      stage_rows<64>(&Kbh[(size_t)(t + 2) * 64 * 64], 64, kt[(t + 2) % 3], wid, lane);
      asm volatile("s_waitcnt vmcnt(4)" ::: "memory");
    } else if (t == 30) {
      asm volatile("s_waitcnt vmcnt(2)" ::: "memory");
    } else {
      asm volatile("s_waitcnt vmcnt(0)" ::: "memory");
    }
    __builtin_amdgcn_sched_barrier(0);
    __builtin_amdgcn_s_barrier();
    const unsigned short* kcur = kt[t % 3];
#pragma unroll
    for (int ks = 0; ks < 4; ++ks) {
      int row = ks * 16 + l15;
      const char* rbase = (const char*)&kcur[row * 64];
      s16x8 a0 = *(const s16x8*)(rbase + ((l4 * 16) ^ ((row & 7) << 4)));
      s16x8 a1 = *(const s16x8*)(rbase + ((64 + l4 * 16) ^ ((row & 7) << 4)));
      f32x4 c0 = {0.f, 0.f, 0.f, 0.f}, c1 = {0.f, 0.f, 0.f, 0.f};
      c0 = __builtin_amdgcn_mfma_f32_16x16x32_bf16(a0, qf[0][0], c0, 0, 0, 0);
      c0 = __builtin_amdgcn_mfma_f32_16x16x32_bf16(a1, qf[0][1], c0, 0, 0, 0);
      c1 = __builtin_amdgcn_mfma_f32_16x16x32_bf16(a0, qf[1][0], c1, 0, 0, 0);
      c1 = __builtin_amdgcn_mfma_f32_16x16x32_bf16(a1, qf[1][1], c1, 0, 0, 0);
      acc0 += __expf(c0[0]) + __expf(c0[1]) + __expf(c0[2]) + __expf(c0[3]);
      acc1 += __expf(c1[0]) + __expf(c1[1]) + __expf(c1[2]) + __expf(c1[3]);
    }
    __builtin_amdgcn_s_barrier();
  }
  acc0 += __shfl_xor(acc0, 16); acc0 += __shfl_xor(acc0, 32);
  acc1 += __shfl_xor(acc1, 16); acc1 += __shfl_xor(acc1, 32);
  float rcpl0 = 1.0f / acc0, rcpl1 = 1.0f / acc1;
  float* wrow0 = &wout[((size_t)bh * 2048 + q0) * 2048];
  float* wrow1 = wrow0 + (size_t)16 * 2048;

  // ---- pass 2: w writes + O = w @ V ----
  f32x4 oacc[2][4];
#pragma unroll
  for (int qg = 0; qg < 2; ++qg)
#pragma unroll
    for (int dt = 0; dt < 4; ++dt) oacc[qg][dt] = {0.f, 0.f, 0.f, 0.f};

  stage_rows<64>(&Kbh[0], 64, kt[0], wid, lane);
  stage_rows<64>(&Vbh[0], 2048, vt[0], wid, lane);
  stage_rows<64>(&Kbh[64 * 64], 64, kt[1], wid, lane);
  stage_rows<64>(&Vbh[64], 2048, vt[1], wid, lane);
  for (int t = 0; t < 32; ++t) {
    int k0 = t * 64;
    if (t < 30) {
      stage_rows<64>(&Kbh[(size_t)(t + 2) * 64 * 64], 64, kt[(t + 2) % 3], wid, lane);
      stage_rows<64>(&Vbh[k0 + 128], 2048, vt[(t + 2) % 3], wid, lane);
      asm volatile("s_waitcnt vmcnt(8)" ::: "memory");
    } else if (t == 30) {
      asm volatile("s_waitcnt vmcnt(4)" ::: "memory");
    } else {
      asm volatile("s_waitcnt vmcnt(0)" ::: "memory");
    }
    __builtin_amdgcn_sched_barrier(0);
    __builtin_amdgcn_s_barrier();
    const unsigned short* kcur = kt[t % 3];
    const unsigned short* vcur = vt[t % 3];

#pragma unroll
    for (int ks = 0; ks < 4; ++ks) {
      int row = ks * 16 + l15;
      const char* rbase = (const char*)&kcur[row * 64];
      s16x8 a0 = *(const s16x8*)(rbase + ((l4 * 16) ^ ((row & 7) << 4)));
      s16x8 a1 = *(const s16x8*)(rbase + ((64 + l4 * 16) ^ ((row & 7) << 4)));
      f32x4 c0 = {0.f, 0.f, 0.f, 0.f}, c1 = {0.f, 0.f, 0.f, 0.f};
      c0 = __builtin_amdgcn_mfma_f32_16x16x32_bf16(a0, qf[0][0], c0, 0, 0, 0);
      c0 = __builtin_amdgcn_mfma_f32_16x16x32_bf16(a1, qf[0][1], c0, 0, 0, 0);
      c1 = __builtin_amdgcn_mfma_f32_16x16x32_bf16(a0, qf[1][0], c1, 0, 0, 0);
      c1 = __builtin_amdgcn_mfma_f32_16x16x32_bf16(a1, qf[1][1], c1, 0, 0, 0);
      float w00 = __expf(c0[0]) * rcpl0, w01 = __expf(c0[1]) * rcpl0;
      float w02 = __expf(c0[2]) * rcpl0, w03 = __expf(c0[3]) * rcpl0;
      float w10 = __expf(c1[0]) * rcpl1, w11 = __expf(c1[1]) * rcpl1;
      float w12 = __expf(c1[2]) * rcpl1, w13 = __expf(c1[3]) * rcpl1;
      ntst4(&wrow0[k0 + ks * 16 + l4 * 4], (f32x4){w00, w01, w02, w03});
      ntst4(&wrow1[k0 + ks * 16 + l4 * 4], (f32x4){w10, w11, w12, w13});
      u16x4 pb0 = {f2bf(w00), f2bf(w01), f2bf(w02), f2bf(w03)};
      u16x4 pb1 = {f2bf(w10), f2bf(w11), f2bf(w12), f2bf(w13)};
      *(u16x4*)((char*)&pt[wid][0][l15 * 64] + ((ks * 32 + l4 * 8) ^ ((l15 & 7) << 4))) = pb0;
      *(u16x4*)((char*)&pt[wid][1][l15 * 64] + ((ks * 32 + l4 * 8) ^ ((l15 & 7) << 4))) = pb1;
    }
    // PV: O[q,d] += P[q,k] * V[k,d]  (pt wave-private)
#pragma unroll
    for (int t2 = 0; t2 < 2; ++t2) {
      s16x8 pa0 = *(const s16x8*)((char*)&pt[wid][0][l15 * 64] +
                                  ((t2 * 64 + l4 * 16) ^ ((l15 & 7) << 4)));
      s16x8 pa1 = *(const s16x8*)((char*)&pt[wid][1][l15 * 64] +
                                  ((t2 * 64 + l4 * 16) ^ ((l15 & 7) << 4)));
#pragma unroll
      for (int dt = 0; dt < 4; ++dt) {
        int vrow = dt * 16 + l15;
        s16x8 vb = *(const s16x8*)((const char*)&vcur[vrow * 64] +
                                   ((t2 * 64 + l4 * 16) ^ ((vrow & 7) << 4)));
        oacc[0][dt] = __builtin_amdgcn_mfma_f32_16x16x32_bf16(pa0, vb, oacc[0][dt], 0, 0, 0);
        oacc[1][dt] = __builtin_amdgcn_mfma_f32_16x16x32_bf16(pa1, vb, oacc[1][dt], 0, 0, 0);
      }
    }
    __builtin_amdgcn_s_barrier();
  }
  int b = bh >> 4, h = bh & 15;
#pragma unroll
  for (int qg = 0; qg < 2; ++qg)
#pragma unroll
    for (int dt = 0; dt < 4; ++dt)
#pragma unroll
      for (int r = 0; r < 4; ++r) {
        int sq = qb + wid * 32 + qg * 16 + l4 * 4 + r;
        int d = dt * 16 + l15;
        wv[(size_t)(b * 2048 + sq) * 1024 + h * 64 + d] = f2bf(oacc[qg][dt][r]);
      }
}

extern "C" void kernel_launch(void* const* d_in, const int* in_sizes, int n_in,
                              void* d_out, int out_size, void* d_ws, size_t ws_size,
                              hipStream_t stream) {
  const float* x  = (const float*)d_in[0];
  const float* Wq = (const float*)d_in[1];
  const float* bq = (const float*)d_in[2];
  const float* Wk = (const float*)d_in[3];
  const float* Wv = (const float*)d_in[4];
  const float* bv = (const float*)d_in[5];
  const float* Wo = (const float*)d_in[6];
  const float* bo = (const float*)d_in[7];
  float* out  = (float*)d_out;
  float* wout = out + 4194304;   // w region of d_out (out is 2*2048*1024)

  // workspace layout (40 MB):
  unsigned short* xb  = (unsigned short*)d_ws;  // 4,194,304 elems (8 MB)
  unsigned short* Wqb = xb + 4194304;           // 1,048,576
  unsigned short* Wkb = Wqb + 1048576;
  unsigned short* Wvb = Wkb + 1048576;
  unsigned short* Wob = Wvb + 1048576;
  unsigned short* Qb  = Wob + 1048576;          // [bh][s][64]  (8 MB)
  unsigned short* Kb  = Qb + 4194304;           // [bh][s][64]  (8 MB)
  unsigned short* Vtb = Kb + 4194304;           // [bh][d][s]   (8 MB)
  unsigned short* wvb = xb;                     // alias: xb dead after V GEMM

  cvt_all<<<8192, 256, 0, stream>>>((const float4*)x, (const float4*)Wq,
                                    (const float4*)Wk, (const float4*)Wv,
                                    (const float4*)Wo,
                                    (u16x4*)xb, (u16x4*)Wqb, (u16x4*)Wkb,
                                    (u16x4*)Wvb, (u16x4*)Wob);

  const float kscale = 0.35355339059327373f;    // 64^-0.25
  gemm_qkv<<<768, 256, 0, stream>>>(xb, Wqb, Wkb, Wvb, bq, bv, Qb, Kb, Vtb, kscale);

  attn_fused<<<512, 256, 0, stream>>>(Qb, Kb, Vtb, wout, wvb);

  gemm_o<<<512, 256, 0, stream>>>(wvb, Wob, bo, out);
}